// Round 10
// baseline (98.846 us; speedup 1.0000x reference)
//
#include <hip/hip_runtime.h>
#include <hip/hip_bf16.h>
#include <math.h>

typedef __attribute__((ext_vector_type(8))) short bf16x8;
typedef __attribute__((ext_vector_type(4))) float f32x4;

#define HW 262144        // 512*512
#define M_SP 1089        // 33*33

// ---- ws layout in 4-byte words ----
#define OFF_CNT1P 0                        // 16*16*8 u32 = 2048
#define OFF_HAB   (OFF_CNT1P + 2048)       // 16*4096 f32 = 65536
#define OFF_HL    (OFF_HAB + 65536)        // 512
#define OFF_W2R   (OFF_HL + 512)           // bf16[9][1024][128] = 589824 words
#define OFF_ZT    (OFF_W2R + 589824)       // bf16[16][37][35][128] = 1326080 words
#define OFF_FEATP (OFF_ZT + 1326080)       // f32[9][16][1024] = 147456 words
// hist 2D partials (16*16*4096 u32 = 1048576 words) alias the zt region:
// prep(hist) -> hist_norm (reads part) -> conv1 (overwrites zt). Sequential on one stream.

__device__ inline unsigned wred_u32(unsigned v) {
#pragma unroll
    for (int off = 32; off > 0; off >>= 1) v += __shfl_down(v, off);
    return v;
}

// ---------------- fused prep: hist (blocks 0..255) + w2 transpose (blocks 256..511) ----------
__global__ __launch_bounds__(512) void prep_kernel(const float* __restrict__ x1,
                                                   const float* __restrict__ w2,
                                                   unsigned* __restrict__ part,
                                                   unsigned* __restrict__ cnt1p,
                                                   __hip_bfloat16* __restrict__ w2r) {
    const int bid = blockIdx.x;
    const int tid = threadIdx.x;

    if (bid >= 256) {
        const int oc = (bid - 256) * 4 + (tid >> 7);
        const int ic = tid & 127;
        const float* src = w2 + oc * 1152 + ic * 9;   // 9 contiguous floats
        float t[9];
#pragma unroll
        for (int k = 0; k < 9; ++k) t[k] = src[k];
#pragma unroll
        for (int k = 0; k < 9; ++k)
            w2r[(k << 17) + (oc << 7) + ic] = __float2bfloat16(t[k]);
        return;
    }

    const int b = bid >> 4, chunk = bid & 15;
    __shared__ unsigned h2[4096];
    __shared__ unsigned wv[8][8];
    for (int i = tid; i < 4096; i += 512) h2[i] = 0u;
    __syncthreads();

    const float4* L4 = (const float4*)(x1 + (size_t)b * 3 * HW);
    const float4* A4 = L4 + 65536;
    const float4* B4 = L4 + 131072;
    const int start = chunk * 4096;

    unsigned long long cL = 0ull;
#pragma unroll 1
    for (int it = 0; it < 8; it += 4) {
        float4 lb[4], ab[4], bbv[4];
#pragma unroll
        for (int u = 0; u < 4; ++u) {
            int idx = start + (it + u) * 512 + tid;
            lb[u] = L4[idx]; ab[u] = A4[idx]; bbv[u] = B4[idx];
        }
#pragma unroll
        for (int u = 0; u < 4; ++u) {
            const float lv[4] = {lb[u].x, lb[u].y, lb[u].z, lb[u].w};
            const float av[4] = {ab[u].x, ab[u].y, ab[u].z, ab[u].w};
            const float bv[4] = {bbv[u].x, bbv[u].y, bbv[u].z, bbv[u].w};
#pragma unroll
            for (int e = 0; e < 4; ++e) {
                float l = lv[e], a = av[e], bb = bv[e];
                float va = (a + 1.f) * 0.5f;
                float vb = (bb + 1.f) * 0.5f;
                if (a != 0.f && bb != 0.f && va >= 0.f && va <= 1.f && vb >= 0.f && vb <= 1.f) {
                    int ia = min(max((int)floorf(va * 64.f), 0), 63);
                    int ib = min(max((int)floorf(vb * 64.f), 0), 63);
                    atomicAdd(&h2[ia * 64 + ib], 1u);
                }
                float vl = (l + 1.f) * 0.5f;
                if (l != 0.f && vl >= 0.f && vl <= 1.f) {
                    int il = min(max((int)floorf(vl * 8.f), 0), 7);
                    cL += 1ull << (il << 3);          // packed byte counters (<=32 each)
                }
            }
        }
    }
    unsigned cc[8];
#pragma unroll
    for (int e = 0; e < 8; ++e) cc[e] = (unsigned)((cL >> (e << 3)) & 0xffull);
#pragma unroll
    for (int e = 0; e < 8; ++e) cc[e] = wred_u32(cc[e]);
    if ((tid & 63) == 0) {
        int w = tid >> 6;
#pragma unroll
        for (int e = 0; e < 8; ++e) wv[w][e] = cc[e];
    }
    __syncthreads();
    if (tid < 8) {
        unsigned s = 0;
#pragma unroll
        for (int w = 0; w < 8; ++w) s += wv[w][tid];
        cnt1p[((size_t)b * 16 + chunk) * 8 + tid] = s;
    }
    uint4* pd = (uint4*)(part + (((size_t)b * 16 + chunk) << 12));
    const uint4* hs = (const uint4*)h2;
    for (int i = tid; i < 1024; i += 512) pd[i] = hs[i];
}

// ---------------- hist_norm: merge partials, normalize, transpose ----------------
__global__ __launch_bounds__(256) void hist_norm(const unsigned* __restrict__ part,
                                                 const unsigned* __restrict__ cnt1p,
                                                 float* __restrict__ hab,
                                                 float* __restrict__ hl) {
    int b = blockIdx.x, tid = threadIdx.x;
    unsigned acc[16];
#pragma unroll
    for (int e = 0; e < 16; ++e) acc[e] = 0u;
#pragma unroll 1
    for (int k = 0; k < 16; ++k) {
        const uint4* p4 = (const uint4*)(part + (((size_t)b * 16 + k) << 12) + tid * 16);
#pragma unroll
        for (int u = 0; u < 4; ++u) {
            uint4 v = p4[u];
            acc[u*4+0] += v.x; acc[u*4+1] += v.y; acc[u*4+2] += v.z; acc[u*4+3] += v.w;
        }
    }
    unsigned ts = 0;
#pragma unroll
    for (int e = 0; e < 16; ++e) ts += acc[e];
    __shared__ float red[256];
    __shared__ float sc8[8];
    red[tid] = (float)ts;
    __syncthreads();
    for (int off = 128; off > 0; off >>= 1) {
        if (tid < off) red[tid] += red[tid + off];
        __syncthreads();
    }
    float inv2 = 1.f / red[0];
    int ia = tid >> 2, ibb = (tid & 3) << 4;
#pragma unroll
    for (int e = 0; e < 16; ++e)
        hab[(b << 12) + ((ibb + e) << 6) + ia] = (float)acc[e] * inv2;
    if (tid < 8) {
        unsigned sc = 0;
        for (int k = 0; k < 16; ++k) sc += cnt1p[((size_t)b * 16 + k) * 8 + tid];
        sc8[tid] = (float)sc;
    }
    __syncthreads();
    if (tid < 8) {
        float tt = 0.f;
#pragma unroll
        for (int c = 0; c < 8; ++c) tt += sc8[c];
        hl[b * 8 + tid] = sc8[tid] / tt;
    }
}

// ---------------- conv1 + BN + maxpool + relu -> zt[b][37][35][128] bf16 (+halo zero) --------
__global__ __launch_bounds__(256) void conv1_pool(
    const float* __restrict__ hab, const float* __restrict__ hl,
    const float* __restrict__ w1, const float* __restrict__ g1,
    const float* __restrict__ b1v, const float* __restrict__ m1,
    const float* __restrict__ v1, __hip_bfloat16* __restrict__ zt)
{
    const int p = blockIdx.x;   // 0..32
    const int b = blockIdx.y;
    __shared__ float aL[128], cL[128], sL[128];
    __shared__ float Hrow[3][64];
    __shared__ float qmx[33], qmn[33];
    __shared__ int qbd[33];
    const int tid = threadIdx.x;
    if (tid < 128) {
        int oc = tid;
        float inv = g1[oc] * rsqrtf(v1[oc] + 1e-5f);
        float s = b1v[oc] - m1[oc] * inv;
        float Kc = 0.f;
#pragma unroll
        for (int c = 1; c < 9; ++c) Kc = fmaf(w1[oc * 9 + c], hl[b * 8 + c - 1], Kc);
        aL[oc] = w1[oc * 9] * inv;
        cL[oc] = fmaf(Kc, inv, s);
        sL[oc] = s;
    }
    if (tid < 192) {
        int rr = tid >> 6, cc = tid & 63;
        int row = 2 * p - 2 + rr;
        Hrow[rr][cc] = (row >= 0 && row < 64) ? hab[b * 4096 + row * 64 + cc] : 0.f;
    }
    __syncthreads();
    if (tid < 33) {
        int q = tid;
        float mx = -1e30f, mn = 1e30f;
        int bd = 0;
#pragma unroll
        for (int dy = 0; dy < 3; ++dy) {
            int yi = 2 * p - 1 + dy;
            if (yi < 0 || yi > 65) continue;
#pragma unroll
            for (int dx = 0; dx < 3; ++dx) {
                int yj = 2 * q - 1 + dx;
                if (yj < 0 || yj > 65) continue;
                if (yi == 0 || yi == 65 || yj == 0 || yj == 65) bd = 1;
                else {
                    float h = Hrow[dy][2 * q - 2 + dx];
                    mx = fmaxf(mx, h); mn = fminf(mn, h);
                }
            }
        }
        qmx[q] = mx; qmn[q] = mn; qbd[q] = bd;
    }
    __syncthreads();
    __hip_bfloat16* zrow = zt + (((size_t)b * 37 + (p + 1)) * 35 + 1) * 128;
    for (int it = tid; it < 33 * 128; it += 256) {
        int q = it >> 7, oc = it & 127;
        float a = aL[oc];
        float v = fmaf(a, (a > 0.f ? qmx[q] : qmn[q]), cL[oc]);
        if (qbd[q]) v = fmaxf(v, sL[oc]);
        v = fmaxf(v, 0.f);
        zrow[q * 128 + oc] = __float2bfloat16(v);
    }
    const __hip_bfloat16 z0 = __float2bfloat16(0.f);
    {
        int col = (tid < 128) ? 0 : 34;
        int ch = tid & 127;
        zt[(((size_t)b * 37 + (p + 1)) * 35 + col) * 128 + ch] = z0;
    }
    if (p < 4) {
        int hr = (p == 0) ? 0 : (33 + p);
        __hip_bfloat16* hrow = zt + ((size_t)b * 37 + hr) * 35 * 128;
        for (int i = tid; i < 35 * 128; i += 256) hrow[i] = z0;
    }
}

// ---------------- conv2: 128x128 tile, BK=32, 3 LDS buffers, counted vmcnt (T4) ----------------
__global__ __launch_bounds__(256, 3) void conv2_mfma(
        const __hip_bfloat16* __restrict__ zt,
        const __hip_bfloat16* __restrict__ w2r,
        const float* __restrict__ g2, const float* __restrict__ b2v,
        const float* __restrict__ m2, const float* __restrict__ v2,
        float* __restrict__ featp)
{
    __shared__ char lds[49152];   // 3 buffers x (A 8KB + B 8KB)
    const int tid = threadIdx.x;
    const int lane = tid & 63, wid = tid >> 6;
    const int b = blockIdx.z;
    const int nbase = blockIdx.x * 128;
    const int mbase = blockIdx.y * 128;
    const int lr16 = lane & 15, lk = lane >> 4;
    const int wm = (wid >> 1) * 64, wn = (wid & 1) * 64;
    // read swizzle: chunk (row, c=lk) lives at phys slot lk ^ ((row>>1)&3); row-dependent part
    // reduces to (lr16>>1)&3 for all frag rows (wm, i*16 are multiples of 8)
    const int koff = ((lk ^ ((lr16 >> 1) & 3)) << 4);

    // staging sources: instr v covers rows wid*32 + v*16 + (lane>>2), phys slot lane&3.
    // source chunk c = (lane&3) ^ g(row), g(row) = (row>>1)&3 = (lane>>3)&3 here.
    const int gsw = (lane >> 3) & 3;
    const int csrc = ((lane & 3) ^ gsw) << 4;
    const char* aS[2];
    const char* bS[2];
    {
        const char* ztb = (const char*)zt + (size_t)b * (37 * 35 * 128 * 2);
#pragma unroll
        for (int v = 0; v < 2; ++v) {
            int row = wid * 32 + v * 16 + (lane >> 2);
            int m = mbase + row;
            int p = m / 33, q = m - p * 33;
            aS[v] = ztb + (p * 35 + q) * 256 + csrc;
            bS[v] = (const char*)w2r + (size_t)(nbase + row) * 256 + csrc;
        }
    }

    f32x4 acc[4][4];
#pragma unroll
    for (int i = 0; i < 4; ++i)
#pragma unroll
        for (int j = 0; j < 4; ++j) acc[i][j] = (f32x4){0.f, 0.f, 0.f, 0.f};

    // stage(s, buf): k-quarter s of the 36 (tap = s>>2, h = s&3)
    auto stage = [&](int s, int buf) {
        const int tap = s >> 2, h = s & 3;
        const int kh = tap / 3, kw = tap - kh * 3;
        const int aoff = (kh * 35 + kw) * 256 + h * 64;
        const int boff = tap * 262144 + h * 64;
        char* ab = lds + buf * 16384 + wid * 2048;
        char* bb = lds + buf * 16384 + 8192 + wid * 2048;
#pragma unroll
        for (int v = 0; v < 2; ++v)
            __builtin_amdgcn_global_load_lds(
                (const __attribute__((address_space(1))) unsigned int*)(aS[v] + aoff),
                (__attribute__((address_space(3))) unsigned int*)(ab + v * 1024), 16, 0, 0);
#pragma unroll
        for (int v = 0; v < 2; ++v)
            __builtin_amdgcn_global_load_lds(
                (const __attribute__((address_space(1))) unsigned int*)(bS[v] + boff),
                (__attribute__((address_space(3))) unsigned int*)(bb + v * 1024), 16, 0, 0);
    };

    auto compute = [&](int buf) {
        const char* Ab = lds + buf * 16384;
        const char* Bb = Ab + 8192;
        bf16x8 af[4], bfr[4];
#pragma unroll
        for (int i = 0; i < 4; ++i)
            af[i] = *(const bf16x8*)(Ab + (wm + i * 16 + lr16) * 64 + koff);
#pragma unroll
        for (int j = 0; j < 4; ++j)
            bfr[j] = *(const bf16x8*)(Bb + (wn + j * 16 + lr16) * 64 + koff);
#pragma unroll
        for (int i = 0; i < 4; ++i)
#pragma unroll
            for (int j = 0; j < 4; ++j)
                acc[i][j] = __builtin_amdgcn_mfma_f32_16x16x32_bf16(af[i], bfr[j], acc[i][j], 0, 0, 0);
    };

#define KBAR(N) \
    asm volatile("s_waitcnt vmcnt(" #N ")" ::: "memory"); \
    __builtin_amdgcn_s_barrier();                          \
    asm volatile("" ::: "memory");

    stage(0, 0); stage(1, 1);          // 8 loads in flight (4/wave... 8 per wave total)
#pragma unroll 1
    for (int s = 0; s < 33; s += 3) {
        KBAR(4) stage(s + 2, 2); compute(0);
        KBAR(4) stage(s + 3, 0); compute(1);
        KBAR(4) stage(s + 4, 1); compute(2);
    }
    KBAR(4) stage(35, 2); compute(0);  // s=33
    KBAR(4) compute(1);                // s=34
    KBAR(0) compute(2);                // s=35
#undef KBAR
    __syncthreads();

    // epilogue: BN2 + ReLU + masked column sums -> featp
    float* red = (float*)lds;   // 8 x 128 floats
#pragma unroll
    for (int j = 0; j < 4; ++j) {
        int nl = wn + j * 16 + lr16;
        int n = nbase + nl;
        float inv = g2[n] * rsqrtf(v2[n] + 1e-5f);
        float sh = b2v[n] - m2[n] * inv;
        float ssum = 0.f;
#pragma unroll
        for (int i = 0; i < 4; ++i) {
            int mlb = wm + i * 16 + lk * 4;
#pragma unroll
            for (int r = 0; r < 4; ++r) {
                if (mbase + mlb + r < M_SP)
                    ssum += fmaxf(fmaf(acc[i][j][r], inv, sh), 0.f);
            }
        }
        red[((wid >> 1) * 4 + lk) * 128 + nl] = ssum;
    }
    __syncthreads();
    if (tid < 128) {
        float s = 0.f;
#pragma unroll
        for (int c = 0; c < 8; ++c) s += red[c * 128 + tid];
        featp[blockIdx.y * 16384 + b * 1024 + nbase + tid] = s * (1.f / 1089.f);
    }
}

// ---------------- head: fused x-copy + feature-sum + linear ----------------
__global__ __launch_bounds__(256) void linear_head(const float* __restrict__ featp,
                                                   const float* __restrict__ x,
                                                   const float* __restrict__ wl,
                                                   const float* __restrict__ bl,
                                                   float* __restrict__ out) {
    int jg = blockIdx.x, b = blockIdx.y;   // grid (16,16)
    __shared__ float fsum[1024];
    int tid = threadIdx.x;
    if (tid < 128)
        out[b * 2304 + jg * 128 + tid] = x[b * 2048 + jg * 128 + tid];
    for (int c = tid; c < 1024; c += 256) {
        float s = 0.f;
#pragma unroll
        for (int mb = 0; mb < 9; ++mb) s += featp[mb * 16384 + b * 1024 + c];
        fsum[c] = s;
    }
    __syncthreads();
    int w = tid >> 6, lane = tid & 63;
#pragma unroll
    for (int jj = 0; jj < 4; ++jj) {
        int j = jg * 16 + w * 4 + jj;
        const float* wr = wl + j * 1024;
        float s = 0.f;
        for (int k = lane; k < 1024; k += 64) s = fmaf(fsum[k], wr[k], s);
#pragma unroll
        for (int off = 32; off > 0; off >>= 1) s += __shfl_down(s, off);
        if (lane == 0) out[b * 2304 + 2048 + j] = s + bl[j];
    }
}

extern "C" void kernel_launch(void* const* d_in, const int* in_sizes, int n_in,
                              void* d_out, int out_size, void* d_ws, size_t ws_size,
                              hipStream_t stream) {
    const float* x  = (const float*)d_in[0];
    const float* x1 = (const float*)d_in[1];
    const float* w1 = (const float*)d_in[2];
    const float* g1 = (const float*)d_in[3];
    const float* b1 = (const float*)d_in[4];
    const float* m1 = (const float*)d_in[5];
    const float* v1 = (const float*)d_in[6];
    const float* w2 = (const float*)d_in[7];
    const float* g2 = (const float*)d_in[8];
    const float* b2 = (const float*)d_in[9];
    const float* m2 = (const float*)d_in[10];
    const float* v2 = (const float*)d_in[11];
    const float* wl = (const float*)d_in[12];
    const float* bl = (const float*)d_in[13];
    float* out = (float*)d_out;

    float* wsf = (float*)d_ws;
    unsigned* cnt1p = (unsigned*)(wsf + OFF_CNT1P);
    float* hab   = wsf + OFF_HAB;
    float* hl    = wsf + OFF_HL;
    __hip_bfloat16* w2r = (__hip_bfloat16*)(wsf + OFF_W2R);
    __hip_bfloat16* zt  = (__hip_bfloat16*)(wsf + OFF_ZT);
    float* featp = wsf + OFF_FEATP;
    unsigned* part = (unsigned*)(wsf + OFF_ZT);   // hist partials alias zt (prep precedes conv1)

    prep_kernel<<<512, 512, 0, stream>>>(x1, w2, part, cnt1p, w2r);
    hist_norm<<<16, 256, 0, stream>>>(part, cnt1p, hab, hl);
    conv1_pool<<<dim3(33, 16), 256, 0, stream>>>(hab, hl, w1, g1, b1, m1, v1, zt);
    conv2_mfma<<<dim3(8, 9, 16), 256, 0, stream>>>(zt, w2r, g2, b2, m2, v2, featp);
    linear_head<<<dim3(16, 16), 256, 0, stream>>>(featp, x, wl, bl, out);
}

// Round 11
// 83.719 us; speedup vs baseline: 1.1807x; 1.1807x over previous
//
#include <hip/hip_runtime.h>
#include <hip/hip_bf16.h>
#include <math.h>

typedef __attribute__((ext_vector_type(8))) short bf16x8;
typedef __attribute__((ext_vector_type(4))) float f32x4;
typedef __attribute__((ext_vector_type(8))) int i32x8;

#define HW 262144        // 512*512
#define M_SP 1089        // 33*33

// ---- ws layout in 4-byte words ----
#define OFF_CNT1P 0                        // 16*16*8 u32 = 2048
#define OFF_HAB   2048                     // 16*4096 f32 = 65536
#define OFF_HL    67584                    // 512
#define OFF_W2R   68096                    // fp8[9][1024][128] = 1179648 B = 294912 words
#define OFF_ZT    362(0+1008)
#undef OFF_ZT
#define OFF_ZT    363008                   // fp8[16][37][35][128] = 2652160 B = 663040 words
#define OFF_FEATP 1026048                  // f32[9][16][1024] = 147456 words
#define OFF_PART  1173504                  // u32[16][16][4096] = 1048576 words

__device__ inline unsigned wred_u32(unsigned v) {
#pragma unroll
    for (int off = 32; off > 0; off >>= 1) v += __shfl_down(v, off);
    return v;
}

// float -> OCP fp8 e4m3 (RNE), no NaN/Inf inputs expected
__device__ inline unsigned char f2e4m3(float x) {
    unsigned s = (__float_as_uint(x) >> 31) << 7;
    float a = fabsf(x);
    if (a >= 464.f) return (unsigned char)(s | 0x7E);       // clamp to 448
    if (a < 0.0009765625f) return (unsigned char)s;         // < 2^-10 -> 0
    int e; float m = frexpf(a, &e); (void)m;                // a = m*2^e, m in [0.5,1)
    int E = e + 6;                                          // biased exponent
    if (E >= 1) {
        float f = ldexpf(a, -(e - 1));                      // in [1,2)
        int q = (int)rintf((f - 1.f) * 8.f);
        if (q == 8) { q = 0; ++E; }
        if (E >= 16) return (unsigned char)(s | 0x7E);
        return (unsigned char)(s | (E << 3) | q);
    } else {
        int q = (int)rintf(ldexpf(a, 9));                   // subnormal: q/8 * 2^-6
        if (q >= 8) return (unsigned char)(s | 0x08);
        return (unsigned char)(s | q);
    }
}

// ---------------- fused prep: hist (blocks 0..255) + w2->fp8 (blocks 256..511) ----------
__global__ __launch_bounds__(512) void prep_kernel(const float* __restrict__ x1,
                                                   const float* __restrict__ w2,
                                                   unsigned* __restrict__ part,
                                                   unsigned* __restrict__ cnt1p,
                                                   unsigned char* __restrict__ w2r) {
    const int bid = blockIdx.x;
    const int tid = threadIdx.x;

    if (bid >= 256) {
        const int oc = (bid - 256) * 4 + (tid >> 7);
        const int ic = tid & 127;
        const float* src = w2 + oc * 1152 + ic * 9;   // 9 contiguous floats
        float t[9];
#pragma unroll
        for (int k = 0; k < 9; ++k) t[k] = src[k];
#pragma unroll
        for (int k = 0; k < 9; ++k)
            w2r[(k << 17) + (oc << 7) + ic] = f2e4m3(t[k]);
        return;
    }

    const int b = bid >> 4, chunk = bid & 15;
    __shared__ unsigned h2[4096];
    __shared__ unsigned wv[8][8];
    for (int i = tid; i < 4096; i += 512) h2[i] = 0u;
    __syncthreads();

    const float4* L4 = (const float4*)(x1 + (size_t)b * 3 * HW);
    const float4* A4 = L4 + 65536;
    const float4* B4 = L4 + 131072;
    const int start = chunk * 4096;

    unsigned long long cL = 0ull;
#pragma unroll 1
    for (int it = 0; it < 8; it += 4) {
        float4 lb[4], ab[4], bbv[4];
#pragma unroll
        for (int u = 0; u < 4; ++u) {
            int idx = start + (it + u) * 512 + tid;
            lb[u] = L4[idx]; ab[u] = A4[idx]; bbv[u] = B4[idx];
        }
#pragma unroll
        for (int u = 0; u < 4; ++u) {
            const float lv[4] = {lb[u].x, lb[u].y, lb[u].z, lb[u].w};
            const float av[4] = {ab[u].x, ab[u].y, ab[u].z, ab[u].w};
            const float bv[4] = {bbv[u].x, bbv[u].y, bbv[u].z, bbv[u].w};
#pragma unroll
            for (int e = 0; e < 4; ++e) {
                float l = lv[e], a = av[e], bb = bv[e];
                float va = (a + 1.f) * 0.5f;
                float vb = (bb + 1.f) * 0.5f;
                if (a != 0.f && bb != 0.f && va >= 0.f && va <= 1.f && vb >= 0.f && vb <= 1.f) {
                    int ia = min(max((int)floorf(va * 64.f), 0), 63);
                    int ib = min(max((int)floorf(vb * 64.f), 0), 63);
                    atomicAdd(&h2[ia * 64 + ib], 1u);
                }
                float vl = (l + 1.f) * 0.5f;
                if (l != 0.f && vl >= 0.f && vl <= 1.f) {
                    int il = min(max((int)floorf(vl * 8.f), 0), 7);
                    cL += 1ull << (il << 3);          // packed byte counters (<=32 each)
                }
            }
        }
    }
    unsigned cc[8];
#pragma unroll
    for (int e = 0; e < 8; ++e) cc[e] = (unsigned)((cL >> (e << 3)) & 0xffull);
#pragma unroll
    for (int e = 0; e < 8; ++e) cc[e] = wred_u32(cc[e]);
    if ((tid & 63) == 0) {
        int w = tid >> 6;
#pragma unroll
        for (int e = 0; e < 8; ++e) wv[w][e] = cc[e];
    }
    __syncthreads();
    if (tid < 8) {
        unsigned s = 0;
#pragma unroll
        for (int w = 0; w < 8; ++w) s += wv[w][tid];
        cnt1p[((size_t)b * 16 + chunk) * 8 + tid] = s;
    }
    uint4* pd = (uint4*)(part + (((size_t)b * 16 + chunk) << 12));
    const uint4* hs = (const uint4*)h2;
    for (int i = tid; i < 1024; i += 512) pd[i] = hs[i];
}

// ---------------- hist_norm: merge partials, normalize, transpose ----------------
__global__ __launch_bounds__(256) void hist_norm(const unsigned* __restrict__ part,
                                                 const unsigned* __restrict__ cnt1p,
                                                 float* __restrict__ hab,
                                                 float* __restrict__ hl) {
    int b = blockIdx.x, tid = threadIdx.x;
    unsigned acc[16];
#pragma unroll
    for (int e = 0; e < 16; ++e) acc[e] = 0u;
#pragma unroll 1
    for (int k = 0; k < 16; ++k) {
        const uint4* p4 = (const uint4*)(part + (((size_t)b * 16 + k) << 12) + tid * 16);
#pragma unroll
        for (int u = 0; u < 4; ++u) {
            uint4 v = p4[u];
            acc[u*4+0] += v.x; acc[u*4+1] += v.y; acc[u*4+2] += v.z; acc[u*4+3] += v.w;
        }
    }
    unsigned ts = 0;
#pragma unroll
    for (int e = 0; e < 16; ++e) ts += acc[e];
    __shared__ float red[256];
    __shared__ float sc8[8];
    red[tid] = (float)ts;
    __syncthreads();
    for (int off = 128; off > 0; off >>= 1) {
        if (tid < off) red[tid] += red[tid + off];
        __syncthreads();
    }
    float inv2 = 1.f / red[0];
    int ia = tid >> 2, ibb = (tid & 3) << 4;
#pragma unroll
    for (int e = 0; e < 16; ++e)
        hab[(b << 12) + ((ibb + e) << 6) + ia] = (float)acc[e] * inv2;
    if (tid < 8) {
        unsigned sc = 0;
        for (int k = 0; k < 16; ++k) sc += cnt1p[((size_t)b * 16 + k) * 8 + tid];
        sc8[tid] = (float)sc;
    }
    __syncthreads();
    if (tid < 8) {
        float tt = 0.f;
#pragma unroll
        for (int c = 0; c < 8; ++c) tt += sc8[c];
        hl[b * 8 + tid] = sc8[tid] / tt;
    }
}

// ---------------- conv1 + BN + maxpool + relu -> zt[b][37][35][128] fp8 (+halo zero) --------
__global__ __launch_bounds__(256) void conv1_pool(
    const float* __restrict__ hab, const float* __restrict__ hl,
    const float* __restrict__ w1, const float* __restrict__ g1,
    const float* __restrict__ b1v, const float* __restrict__ m1,
    const float* __restrict__ v1, unsigned char* __restrict__ zt)
{
    const int p = blockIdx.x;   // 0..32
    const int b = blockIdx.y;
    __shared__ float aL[128], cL[128], sL[128];
    __shared__ float Hrow[3][64];
    __shared__ float qmx[33], qmn[33];
    __shared__ int qbd[33];
    const int tid = threadIdx.x;
    if (tid < 128) {
        int oc = tid;
        float inv = g1[oc] * rsqrtf(v1[oc] + 1e-5f);
        float s = b1v[oc] - m1[oc] * inv;
        float Kc = 0.f;
#pragma unroll
        for (int c = 1; c < 9; ++c) Kc = fmaf(w1[oc * 9 + c], hl[b * 8 + c - 1], Kc);
        aL[oc] = w1[oc * 9] * inv;
        cL[oc] = fmaf(Kc, inv, s);
        sL[oc] = s;
    }
    if (tid < 192) {
        int rr = tid >> 6, cc = tid & 63;
        int row = 2 * p - 2 + rr;
        Hrow[rr][cc] = (row >= 0 && row < 64) ? hab[b * 4096 + row * 64 + cc] : 0.f;
    }
    __syncthreads();
    if (tid < 33) {
        int q = tid;
        float mx = -1e30f, mn = 1e30f;
        int bd = 0;
#pragma unroll
        for (int dy = 0; dy < 3; ++dy) {
            int yi = 2 * p - 1 + dy;
            if (yi < 0 || yi > 65) continue;
#pragma unroll
            for (int dx = 0; dx < 3; ++dx) {
                int yj = 2 * q - 1 + dx;
                if (yj < 0 || yj > 65) continue;
                if (yi == 0 || yi == 65 || yj == 0 || yj == 65) bd = 1;
                else {
                    float h = Hrow[dy][2 * q - 2 + dx];
                    mx = fmaxf(mx, h); mn = fminf(mn, h);
                }
            }
        }
        qmx[q] = mx; qmn[q] = mn; qbd[q] = bd;
    }
    __syncthreads();
    unsigned char* zrow = zt + (((size_t)b * 37 + (p + 1)) * 35 + 1) * 128;
    for (int it = tid; it < 33 * 128; it += 256) {
        int q = it >> 7, oc = it & 127;
        float a = aL[oc];
        float v = fmaf(a, (a > 0.f ? qmx[q] : qmn[q]), cL[oc]);
        if (qbd[q]) v = fmaxf(v, sL[oc]);
        v = fmaxf(v, 0.f);
        zrow[q * 128 + oc] = f2e4m3(v);
    }
    // ---- halo zeroing ----
    {
        int col = (tid < 128) ? 0 : 34;
        int ch = tid & 127;
        zt[(((size_t)b * 37 + (p + 1)) * 35 + col) * 128 + ch] = 0;
    }
    if (p < 4) {
        int hr = (p == 0) ? 0 : (33 + p);
        unsigned char* hrow = zt + ((size_t)b * 37 + hr) * 35 * 128;
        for (int i = tid; i < 35 * 128; i += 256) hrow[i] = 0;
    }
}

// ---------------- conv2: 9 tap-GEMMs, MX-fp8 K=128 MFMA, fused BN+ReLU+mean ----------------
__global__ __launch_bounds__(256, 2) void conv2_mfma(
        const unsigned char* __restrict__ zt,
        const unsigned char* __restrict__ w2r,
        const float* __restrict__ g2, const float* __restrict__ b2v,
        const float* __restrict__ m2, const float* __restrict__ v2,
        float* __restrict__ featp)
{
    __shared__ char lds[65536];   // 2 buffers x (A 16KB + B 16KB)
    const int tid = threadIdx.x;
    const int lane = tid & 63, wid = tid >> 6;
    const int b = blockIdx.z;
    const int nbase = blockIdx.x * 128;
    const int mbase = blockIdx.y * 128;
    const int lr16 = lane & 15, lk = lane >> 4;
    const int wm = (wid >> 1) * 64, wn = (wid & 1) * 64;

    // staging: instr v covers rows R = wid*32 + v*8 + (lane>>3); phys slot = lane&7.
    // pre-XOR source chunk: csrc = (slot ^ (R&7)) * 16 ; R&7 == lane>>3 here.
    const int csrc = ((lane & 7) ^ (lane >> 3)) << 4;
    const unsigned char* aS[4];
    const unsigned char* bS[4];
    {
        const unsigned char* ztb = zt + (size_t)b * 165760;   // 37*35*128
#pragma unroll
        for (int v = 0; v < 4; ++v) {
            int R = wid * 32 + v * 8 + (lane >> 3);
            int m = mbase + R;
            int p = m / 33, q = m - p * 33;
            aS[v] = ztb + (p * 35 + q) * 128 + csrc;
            bS[v] = w2r + (size_t)(nbase + R) * 128 + csrc;
        }
    }

    f32x4 acc[4][4];
#pragma unroll
    for (int i = 0; i < 4; ++i)
#pragma unroll
        for (int j = 0; j < 4; ++j) acc[i][j] = (f32x4){0.f, 0.f, 0.f, 0.f};

    auto stage = [&](int d, int tap) {
        const int kh = tap / 3, kw = tap - kh * 3;
        const int aoff = (kh * 35 + kw) * 128;
        const int boff = tap * 131072;
        char* ab = lds + d * 32768 + wid * 4096;
        char* bb = ab + 16384;
#pragma unroll
        for (int v = 0; v < 4; ++v)
            __builtin_amdgcn_global_load_lds(
                (const __attribute__((address_space(1))) unsigned int*)(aS[v] + aoff),
                (__attribute__((address_space(3))) unsigned int*)(ab + v * 1024), 16, 0, 0);
#pragma unroll
        for (int v = 0; v < 4; ++v)
            __builtin_amdgcn_global_load_lds(
                (const __attribute__((address_space(1))) unsigned int*)(bS[v] + boff),
                (__attribute__((address_space(3))) unsigned int*)(bb + v * 1024), 16, 0, 0);
    };

    auto compute = [&](int d) {
        const char* Ab = lds + d * 32768;
        const char* Bb = Ab + 16384;
        i32x8 af[4], bf[4];
#pragma unroll
        for (int i = 0; i < 4; ++i) {
            int row = wm + i * 16 + lr16;
            const char* base = Ab + row * 128;
            int x = row & 7;
            int4 lo = *(const int4*)(base + (((2 * lk) ^ x) << 4));
            int4 hi = *(const int4*)(base + (((2 * lk + 1) ^ x) << 4));
            af[i] = (i32x8){lo.x, lo.y, lo.z, lo.w, hi.x, hi.y, hi.z, hi.w};
        }
#pragma unroll
        for (int j = 0; j < 4; ++j) {
            int row = wn + j * 16 + lr16;
            const char* base = Bb + row * 128;
            int x = row & 7;
            int4 lo = *(const int4*)(base + (((2 * lk) ^ x) << 4));
            int4 hi = *(const int4*)(base + (((2 * lk + 1) ^ x) << 4));
            bf[j] = (i32x8){lo.x, lo.y, lo.z, lo.w, hi.x, hi.y, hi.z, hi.w};
        }
#pragma unroll
        for (int i = 0; i < 4; ++i)
#pragma unroll
            for (int j = 0; j < 4; ++j)
                acc[i][j] = __builtin_amdgcn_mfma_scale_f32_16x16x128_f8f6f4(
                    af[i], bf[j], acc[i][j],
                    0, 0,                       // cbsz = fp8 e4m3, blgp = fp8 e4m3
                    0, 0x7F7F7F7F,              // scale A: opsel 0, e8m0 = 1.0
                    0, 0x7F7F7F7F);             // scale B
    };

    stage(0, 0);
    __syncthreads();
#pragma unroll 1
    for (int s = 0; s < 9; ++s) {
        if (s < 8) stage((s + 1) & 1, s + 1);
        compute(s & 1);
        __syncthreads();
    }

    // epilogue: BN2 + ReLU + masked column sums -> featp
    float* red = (float*)lds;   // 8 x 128 floats
#pragma unroll
    for (int j = 0; j < 4; ++j) {
        int nl = wn + j * 16 + lr16;
        int n = nbase + nl;
        float inv = g2[n] * rsqrtf(v2[n] + 1e-5f);
        float sh = b2v[n] - m2[n] * inv;
        float ssum = 0.f;
#pragma unroll
        for (int i = 0; i < 4; ++i) {
            int mlb = wm + i * 16 + lk * 4;
#pragma unroll
            for (int r = 0; r < 4; ++r) {
                if (mbase + mlb + r < M_SP)
                    ssum += fmaxf(fmaf(acc[i][j][r], inv, sh), 0.f);
            }
        }
        red[((wid >> 1) * 4 + lk) * 128 + nl] = ssum;
    }
    __syncthreads();
    if (tid < 128) {
        float s = 0.f;
#pragma unroll
        for (int c = 0; c < 8; ++c) s += red[c * 128 + tid];
        featp[blockIdx.y * 16384 + b * 1024 + nbase + tid] = s * (1.f / 1089.f);
    }
}

// ---------------- head: fused x-copy + feature-sum + linear ----------------
__global__ __launch_bounds__(256) void linear_head(const float* __restrict__ featp,
                                                   const float* __restrict__ x,
                                                   const float* __restrict__ wl,
                                                   const float* __restrict__ bl,
                                                   float* __restrict__ out) {
    int jg = blockIdx.x, b = blockIdx.y;   // grid (16,16)
    __shared__ float fsum[1024];
    int tid = threadIdx.x;
    if (tid < 128)
        out[b * 2304 + jg * 128 + tid] = x[b * 2048 + jg * 128 + tid];
    for (int c = tid; c < 1024; c += 256) {
        float s = 0.f;
#pragma unroll
        for (int mb = 0; mb < 9; ++mb) s += featp[mb * 16384 + b * 1024 + c];
        fsum[c] = s;
    }
    __syncthreads();
    int w = tid >> 6, lane = tid & 63;
#pragma unroll
    for (int jj = 0; jj < 4; ++jj) {
        int j = jg * 16 + w * 4 + jj;
        const float* wr = wl + j * 1024;
        float s = 0.f;
        for (int k = lane; k < 1024; k += 64) s = fmaf(fsum[k], wr[k], s);
#pragma unroll
        for (int off = 32; off > 0; off >>= 1) s += __shfl_down(s, off);
        if (lane == 0) out[b * 2304 + 2048 + j] = s + bl[j];
    }
}

extern "C" void kernel_launch(void* const* d_in, const int* in_sizes, int n_in,
                              void* d_out, int out_size, void* d_ws, size_t ws_size,
                              hipStream_t stream) {
    const float* x  = (const float*)d_in[0];
    const float* x1 = (const float*)d_in[1];
    const float* w1 = (const float*)d_in[2];
    const float* g1 = (const float*)d_in[3];
    const float* b1 = (const float*)d_in[4];
    const float* m1 = (const float*)d_in[5];
    const float* v1 = (const float*)d_in[6];
    const float* w2 = (const float*)d_in[7];
    const float* g2 = (const float*)d_in[8];
    const float* b2 = (const float*)d_in[9];
    const float* m2 = (const float*)d_in[10];
    const float* v2 = (const float*)d_in[11];
    const float* wl = (const float*)d_in[12];
    const float* bl = (const float*)d_in[13];
    float* out = (float*)d_out;

    float* wsf = (float*)d_ws;
    unsigned* cnt1p = (unsigned*)(wsf + OFF_CNT1P);
    float* hab   = wsf + OFF_HAB;
    float* hl    = wsf + OFF_HL;
    unsigned char* w2r = (unsigned char*)(wsf + OFF_W2R);
    unsigned char* zt  = (unsigned char*)(wsf + OFF_ZT);
    float* featp = wsf + OFF_FEATP;
    unsigned* part = (unsigned*)(wsf + OFF_PART);

    prep_kernel<<<512, 512, 0, stream>>>(x1, w2, part, cnt1p, w2r);
    hist_norm<<<16, 256, 0, stream>>>(part, cnt1p, hab, hl);
    conv1_pool<<<dim3(33, 16), 256, 0, stream>>>(hab, hl, w1, g1, b1, m1, v1, zt);
    conv2_mfma<<<dim3(8, 9, 16), 256, 0, stream>>>(zt, w2r, g2, b2, m2, v2, featp);
    linear_head<<<dim3(16, 16), 256, 0, stream>>>(featp, x, wl, bl, out);
}